// Round 2
// baseline (942.138 us; speedup 1.0000x reference)
//
#include <hip/hip_runtime.h>

#define D 64
#define NG 512

// ---------------- edge pass: degree + per-node in-edge histogram ----------------
__global__ __launch_bounds__(256) void k_edge_deg(const int* __restrict__ src,
                                                  const int* __restrict__ dst,
                                                  const float* __restrict__ w,
                                                  float* __restrict__ deg,
                                                  int* __restrict__ cnt, int E) {
    int e = blockIdx.x * 256 + threadIdx.x;
    if (e < E) {
        int d = dst[e];
        atomicAdd(&deg[d], w[e]);
        atomicAdd(&cnt[d], 1);
    }
}

// ---------------- node pass: dinv = 1/sqrt(deg+1), graph counts ----------------
__global__ __launch_bounds__(256) void k_node_dinv(const float* __restrict__ deg,
                                                   float* __restrict__ dinv,
                                                   const int* __restrict__ batch,
                                                   int* __restrict__ gcnt, int N) {
    int n = blockIdx.x * 256 + threadIdx.x;
    if (n < N) {
        // full-precision: dinv multiplies into every edge coeff of all 3 layers;
        // v_rsq_f32's ~1e-6 rel error would compound against the JAX reference.
        dinv[n] = 1.0f / sqrtf(deg[n] + 1.0f);
        atomicAdd(&gcnt[batch[n]], 1);
    }
}

// ---------------- exclusive scan of padded counts (3 kernels) ----------------
// scan input = (cnt+3)&~3 so each node's CSR slice starts 16B-aligned.
__global__ __launch_bounds__(256) void k_scan1(const int* __restrict__ cnt,
                                               int* __restrict__ rp,
                                               int* __restrict__ bsums, int N) {
    __shared__ int s[256];
    int t = threadIdx.x;
    int i = blockIdx.x * 256 + t;
    int v = (i < N) ? ((cnt[i] + 3) & ~3) : 0;
    s[t] = v;
    __syncthreads();
    for (int off = 1; off < 256; off <<= 1) {
        int a = (t >= off) ? s[t - off] : 0;
        __syncthreads();
        s[t] += a;
        __syncthreads();
    }
    if (i < N) rp[i] = s[t] - v;            // block-local exclusive
    if (t == 255) bsums[blockIdx.x] = s[255];
}

__global__ __launch_bounds__(512) void k_scan2(int* __restrict__ bsums, int nb) {
    __shared__ int s[512];
    int t = threadIdx.x;
    int v = (t < nb) ? bsums[t] : 0;
    s[t] = v;
    __syncthreads();
    for (int off = 1; off < 512; off <<= 1) {
        int a = (t >= off) ? s[t - off] : 0;
        __syncthreads();
        s[t] += a;
        __syncthreads();
    }
    if (t < nb) bsums[t] = s[t] - v;        // exclusive block offsets
}

__global__ __launch_bounds__(256) void k_scan3(int* __restrict__ rp,
                                               const int* __restrict__ bsums, int N) {
    int i = blockIdx.x * 256 + threadIdx.x;
    if (i < N) rp[i] += bsums[blockIdx.x];
}

// ---------------- CSR fill: col + fused norm coefficient ----------------
__global__ __launch_bounds__(256) void k_fill(const int* __restrict__ src,
                                              const int* __restrict__ dst,
                                              const float* __restrict__ w,
                                              const float* __restrict__ dinv,
                                              const int* __restrict__ rp,
                                              int* __restrict__ fill,
                                              int* __restrict__ col,
                                              float* __restrict__ val, int E) {
    int e = blockIdx.x * 256 + threadIdx.x;
    if (e < E) {
        int s0 = src[e], d0 = dst[e];
        int pos = rp[d0] + atomicAdd(&fill[d0], 1);
        col[pos] = s0;
        val[pos] = dinv[s0] * w[e] * dinv[d0];
    }
}

// ---------------- GEMM: C[N,64] = A[N,64] @ W[64,64] (fp32 vector) ----------------
__global__ __launch_bounds__(256) void k_gemm(const float* __restrict__ A,
                                              const float* __restrict__ W,
                                              float* __restrict__ C, int N) {
    __shared__ float sW[64 * 64];
    __shared__ float sA[64 * 64];
    int t = threadIdx.x;
    int rb = blockIdx.x * 64;
    #pragma unroll
    for (int i = 0; i < 16; i++) sW[t + 256 * i] = W[t + 256 * i];
    #pragma unroll
    for (int i = 0; i < 16; i++) {
        int idx = t + 256 * i;
        int r = rb + (idx >> 6);
        sA[idx] = (r < N) ? A[(size_t)r * D + (idx & 63)] : 0.0f;
    }
    __syncthreads();
    int tx = t & 15, ty = t >> 4;           // 16x16 threads, 4x4 micro-tile
    float acc[4][4] = {};
    #pragma unroll
    for (int k = 0; k < 64; k++) {
        float4 wv = *(const float4*)&sW[k * 64 + tx * 4];
        float h0 = sA[(ty * 4 + 0) * 64 + k];
        float h1 = sA[(ty * 4 + 1) * 64 + k];
        float h2 = sA[(ty * 4 + 2) * 64 + k];
        float h3 = sA[(ty * 4 + 3) * 64 + k];
        acc[0][0] += h0 * wv.x; acc[0][1] += h0 * wv.y; acc[0][2] += h0 * wv.z; acc[0][3] += h0 * wv.w;
        acc[1][0] += h1 * wv.x; acc[1][1] += h1 * wv.y; acc[1][2] += h1 * wv.z; acc[1][3] += h1 * wv.w;
        acc[2][0] += h2 * wv.x; acc[2][1] += h2 * wv.y; acc[2][2] += h2 * wv.z; acc[2][3] += h2 * wv.w;
        acc[3][0] += h3 * wv.x; acc[3][1] += h3 * wv.y; acc[3][2] += h3 * wv.z; acc[3][3] += h3 * wv.w;
    }
    #pragma unroll
    for (int i = 0; i < 4; i++) {
        int r = rb + ty * 4 + i;
        if (r < N) {
            float4 o = make_float4(acc[i][0], acc[i][1], acc[i][2], acc[i][3]);
            *(float4*)&C[(size_t)r * D + tx * 4] = o;
        }
    }
}

// ---------------- aggregate: h_out[n] = b + self*hW[n] + sum_e val*hW[col] ----------------
// one wave per node; lane = channel. No float atomics.
template <int RELU>
__global__ __launch_bounds__(256) void k_agg(const float* __restrict__ hW,
                                             const int* __restrict__ rp,
                                             const int* __restrict__ cnt,
                                             const int* __restrict__ col,
                                             const float* __restrict__ val,
                                             const float* __restrict__ dinv,
                                             const float* __restrict__ bias,
                                             float* __restrict__ hout, int N) {
    int lane = threadIdx.x & 63;
    int n = blockIdx.x * 4 + (threadIdx.x >> 6);
    if (n >= N) return;
    float dv = dinv[n];
    float acc = bias[lane] + dv * dv * hW[(size_t)n * D + lane];
    int r0 = rp[n], c = cnt[n];
    int i = 0, c4 = c & ~3;
    for (; i < c4; i += 4) {
        int4  s4 = *(const int4*)(col + r0 + i);
        float4 v4 = *(const float4*)(val + r0 + i);
        acc += v4.x * hW[(size_t)s4.x * D + lane];
        acc += v4.y * hW[(size_t)s4.y * D + lane];
        acc += v4.z * hW[(size_t)s4.z * D + lane];
        acc += v4.w * hW[(size_t)s4.w * D + lane];
    }
    for (; i < c; i++) acc += val[r0 + i] * hW[(size_t)col[r0 + i] * D + lane];
    if (RELU) acc = fmaxf(acc, 0.0f);
    hout[(size_t)n * D + lane] = acc;
}

// ---------------- final layer: aggregate (no relu) + MLP readout + graph-sum ----------------
__global__ __launch_bounds__(256) void k_agg_readout(const float* __restrict__ hW,
                                                     const int* __restrict__ rp,
                                                     const int* __restrict__ cnt,
                                                     const int* __restrict__ col,
                                                     const float* __restrict__ val,
                                                     const float* __restrict__ dinv,
                                                     const float* __restrict__ bias,
                                                     const float* __restrict__ RW1,
                                                     const float* __restrict__ Rb1,
                                                     const float* __restrict__ RW2,
                                                     const float* __restrict__ Rb2,
                                                     const int* __restrict__ batch,
                                                     float* __restrict__ gsum, int N) {
    __shared__ float sh[4][64];
    int lane = threadIdx.x & 63;
    int widx = threadIdx.x >> 6;
    int n = blockIdx.x * 4 + widx;
    bool valid = (n < N);
    float acc = 0.0f;
    if (valid) {
        float dv = dinv[n];
        acc = bias[lane] + dv * dv * hW[(size_t)n * D + lane];
        int r0 = rp[n], c = cnt[n];
        int i = 0, c4 = c & ~3;
        for (; i < c4; i += 4) {
            int4  s4 = *(const int4*)(col + r0 + i);
            float4 v4 = *(const float4*)(val + r0 + i);
            acc += v4.x * hW[(size_t)s4.x * D + lane];
            acc += v4.y * hW[(size_t)s4.y * D + lane];
            acc += v4.z * hW[(size_t)s4.z * D + lane];
            acc += v4.w * hW[(size_t)s4.w * D + lane];
        }
        for (; i < c; i++) acc += val[r0 + i] * hW[(size_t)col[r0 + i] * D + lane];
    }
    sh[widx][lane] = acc;         // h2 (no relu on last GCN layer)
    __syncthreads();
    if (valid && lane < 32) {
        float m = Rb1[lane];
        #pragma unroll
        for (int cc = 0; cc < 64; cc++) m += sh[widx][cc] * RW1[cc * 32 + lane];
        m = fmaxf(m, 0.0f);
        float y = m * RW2[lane];
        #pragma unroll
        for (int off = 16; off; off >>= 1) y += __shfl_down(y, off, 32);
        if (lane == 0) atomicAdd(&gsum[batch[n]], y + Rb2[0]);
    }
}

// ---------------- scatter-mean finalize ----------------
__global__ __launch_bounds__(256) void k_final(const float* __restrict__ gsum,
                                               const int* __restrict__ gcnt,
                                               float* __restrict__ out, int G) {
    int g = blockIdx.x * 256 + threadIdx.x;
    if (g < G) out[g] = gsum[g] / fmaxf((float)gcnt[g], 1.0f);
}

extern "C" void kernel_launch(void* const* d_in, const int* in_sizes, int n_in,
                              void* d_out, int out_size, void* d_ws, size_t ws_size,
                              hipStream_t stream) {
    const float* x     = (const float*)d_in[0];
    const int*   ei    = (const int*)d_in[1];
    const float* ea    = (const float*)d_in[2];
    const int*   batch = (const int*)d_in[3];
    const float* W0 = (const float*)d_in[4];
    const float* b0 = (const float*)d_in[5];
    const float* W1 = (const float*)d_in[6];
    const float* b1 = (const float*)d_in[7];
    const float* W2 = (const float*)d_in[8];
    const float* b2 = (const float*)d_in[9];
    const float* RW1 = (const float*)d_in[10];
    const float* Rb1 = (const float*)d_in[11];
    const float* RW2 = (const float*)d_in[12];
    const float* Rb2 = (const float*)d_in[13];

    const int N = in_sizes[0] / D;        // 100000
    const int E = in_sizes[1] / 2;        // 1200000
    const int G = out_size;               // 512
    const int* src = ei;
    const int* dst = ei + E;

    // ---- workspace layout ----
    char* p = (char*)d_ws;
    // zero-init region (one memset): deg, cnt_node, fill, gsum, gcnt
    float* deg   = (float*)p;             p += (size_t)N * 4;
    int*   cnt   = (int*)p;               p += (size_t)N * 4;
    int*   fill  = (int*)p;               p += (size_t)N * 4;
    float* gsum  = (float*)p;             p += (size_t)NG * 4;
    int*   gcnt  = (int*)p;               p += (size_t)NG * 4;
    size_t zbytes = (size_t)(3 * N + 2 * NG) * 4;
    // no-init region
    float* dinv  = (float*)p;             p += (size_t)N * 4;
    int*   rp    = (int*)p;               p += (size_t)N * 4;
    int*   bsums = (int*)p;               p += (size_t)512 * 4;
    const size_t EP = (size_t)E + 4 * (size_t)N;   // padded CSR capacity
    int*   col   = (int*)p;               p += EP * 4;
    float* val   = (float*)p;             p += EP * 4;
    float* hW    = (float*)p;             p += (size_t)N * D * 4;
    float* h     = (float*)p;             p += (size_t)N * D * 4;

    hipMemsetAsync(d_ws, 0, zbytes, stream);

    int ebl = (E + 255) / 256;
    int nbl = (N + 255) / 256;            // 391
    k_edge_deg<<<ebl, 256, 0, stream>>>(src, dst, ea, deg, cnt, E);
    k_node_dinv<<<nbl, 256, 0, stream>>>(deg, dinv, batch, gcnt, N);
    k_scan1<<<nbl, 256, 0, stream>>>(cnt, rp, bsums, N);
    k_scan2<<<1, 512, 0, stream>>>(bsums, nbl);
    k_scan3<<<nbl, 256, 0, stream>>>(rp, bsums, N);
    k_fill<<<ebl, 256, 0, stream>>>(src, dst, ea, dinv, rp, fill, col, val, E);

    int gemm_bl = (N + 63) / 64;          // 1563
    int agg_bl  = (N + 3) / 4;            // 25000

    // layer 0: x -> h
    k_gemm<<<gemm_bl, 256, 0, stream>>>(x, W0, hW, N);
    k_agg<1><<<agg_bl, 256, 0, stream>>>(hW, rp, cnt, col, val, dinv, b0, h, N);
    // layer 1: h -> h
    k_gemm<<<gemm_bl, 256, 0, stream>>>(h, W1, hW, N);
    k_agg<1><<<agg_bl, 256, 0, stream>>>(hW, rp, cnt, col, val, dinv, b1, h, N);
    // layer 2 + readout + graph scatter
    k_gemm<<<gemm_bl, 256, 0, stream>>>(h, W2, hW, N);
    k_agg_readout<<<agg_bl, 256, 0, stream>>>(hW, rp, cnt, col, val, dinv, b2,
                                              RW1, Rb1, RW2, Rb2, batch, gsum, N);

    k_final<<<(G + 255) / 256, 256, 0, stream>>>(gsum, gcnt, d_out ? (float*)d_out : nullptr, G);
}

// Round 4
// 890.108 us; speedup vs baseline: 1.0585x; 1.0585x over previous
//
#include <hip/hip_runtime.h>

#define D 64
#define NG 512

// ---------------- edge pass: degree + per-node in-edge histogram ----------------
__global__ __launch_bounds__(256) void k_edge_deg(const int* __restrict__ src,
                                                  const int* __restrict__ dst,
                                                  const float* __restrict__ w,
                                                  float* __restrict__ deg,
                                                  int* __restrict__ cnt, int E) {
    int e = blockIdx.x * 256 + threadIdx.x;
    if (e < E) {
        int d = dst[e];
        atomicAdd(&deg[d], w[e]);
        atomicAdd(&cnt[d], 1);
    }
}

// ---------------- node pass: dinv = 1/sqrt(deg+1), graph counts ----------------
__global__ __launch_bounds__(256) void k_node_dinv(const float* __restrict__ deg,
                                                   float* __restrict__ dinv,
                                                   const int* __restrict__ batch,
                                                   int* __restrict__ gcnt, int N) {
    int n = blockIdx.x * 256 + threadIdx.x;
    if (n < N) {
        // full precision: dinv multiplies into every edge coeff of all 3 layers
        dinv[n] = 1.0f / sqrtf(deg[n] + 1.0f);
        atomicAdd(&gcnt[batch[n]], 1);
    }
}

// ---------------- exclusive scan of padded counts (3 kernels) ----------------
// scan input = (cnt+7)&~7: each node's CSR slice is a whole number of 8-edge
// groups; pad slots are pre-zeroed (col=0, val=0 -> contributes 0).
__global__ __launch_bounds__(256) void k_scan1(const int* __restrict__ cnt,
                                               int* __restrict__ rp,
                                               int* __restrict__ bsums, int N) {
    __shared__ int s[256];
    int t = threadIdx.x;
    int i = blockIdx.x * 256 + t;
    int v = (i < N) ? ((cnt[i] + 7) & ~7) : 0;
    s[t] = v;
    __syncthreads();
    for (int off = 1; off < 256; off <<= 1) {
        int a = (t >= off) ? s[t - off] : 0;
        __syncthreads();
        s[t] += a;
        __syncthreads();
    }
    if (i < N) rp[i] = s[t] - v;            // block-local exclusive
    if (t == 255) bsums[blockIdx.x] = s[255];
}

__global__ __launch_bounds__(512) void k_scan2(int* __restrict__ bsums, int nb) {
    __shared__ int s[512];
    int t = threadIdx.x;
    int v = (t < nb) ? bsums[t] : 0;
    s[t] = v;
    __syncthreads();
    for (int off = 1; off < 512; off <<= 1) {
        int a = (t >= off) ? s[t - off] : 0;
        __syncthreads();
        s[t] += a;
        __syncthreads();
    }
    if (t < nb) bsums[t] = s[t] - v;        // exclusive block offsets
}

__global__ __launch_bounds__(256) void k_scan3(int* __restrict__ rp,
                                               const int* __restrict__ bsums, int N) {
    int i = blockIdx.x * 256 + threadIdx.x;
    if (i < N) rp[i] += bsums[blockIdx.x];
}

// ---------------- CSR fill: packed (col, norm) int2 ----------------
__global__ __launch_bounds__(256) void k_fill(const int* __restrict__ src,
                                              const int* __restrict__ dst,
                                              const float* __restrict__ w,
                                              const float* __restrict__ dinv,
                                              const int* __restrict__ rp,
                                              int* __restrict__ fill,
                                              int2* __restrict__ pack, int E) {
    int e = blockIdx.x * 256 + threadIdx.x;
    if (e < E) {
        int s0 = src[e], d0 = dst[e];
        int pos = rp[d0] + atomicAdd(&fill[d0], 1);
        pack[pos] = make_int2(s0, __float_as_int(dinv[s0] * w[e] * dinv[d0]));
    }
}

// ---------------- GEMM: C[N,64] = A[N,64] @ W[64,64] (fp32 vector) ----------------
__global__ __launch_bounds__(256) void k_gemm(const float* __restrict__ A,
                                              const float* __restrict__ W,
                                              float* __restrict__ C, int N) {
    __shared__ float sW[64 * 64];
    __shared__ float sA[64 * 64];
    int t = threadIdx.x;
    int rb = blockIdx.x * 64;
    #pragma unroll
    for (int i = 0; i < 16; i++) sW[t + 256 * i] = W[t + 256 * i];
    #pragma unroll
    for (int i = 0; i < 16; i++) {
        int idx = t + 256 * i;
        int r = rb + (idx >> 6);
        sA[idx] = (r < N) ? A[(size_t)r * D + (idx & 63)] : 0.0f;
    }
    __syncthreads();
    int tx = t & 15, ty = t >> 4;           // 16x16 threads, 4x4 micro-tile
    float acc[4][4] = {};
    #pragma unroll
    for (int k = 0; k < 64; k++) {
        float4 wv = *(const float4*)&sW[k * 64 + tx * 4];
        float h0 = sA[(ty * 4 + 0) * 64 + k];
        float h1 = sA[(ty * 4 + 1) * 64 + k];
        float h2 = sA[(ty * 4 + 2) * 64 + k];
        float h3 = sA[(ty * 4 + 3) * 64 + k];
        acc[0][0] += h0 * wv.x; acc[0][1] += h0 * wv.y; acc[0][2] += h0 * wv.z; acc[0][3] += h0 * wv.w;
        acc[1][0] += h1 * wv.x; acc[1][1] += h1 * wv.y; acc[1][2] += h1 * wv.z; acc[1][3] += h1 * wv.w;
        acc[2][0] += h2 * wv.x; acc[2][1] += h2 * wv.y; acc[2][2] += h2 * wv.z; acc[2][3] += h2 * wv.w;
        acc[3][0] += h3 * wv.x; acc[3][1] += h3 * wv.y; acc[3][2] += h3 * wv.z; acc[3][3] += h3 * wv.w;
    }
    #pragma unroll
    for (int i = 0; i < 4; i++) {
        int r = rb + ty * 4 + i;
        if (r < N) {
            float4 o = make_float4(acc[i][0], acc[i][1], acc[i][2], acc[i][3]);
            *(float4*)&C[(size_t)r * D + tx * 4] = o;
        }
    }
}

// ---------------- aggregate, 4-rows-per-instruction gather ----------------
// one wave per node. Lane layout: grp = lane>>4 picks edge-in-quad, 16 lanes
// x float4 cover one 256B row. 8 edges (2 gather instrs) in flight per iter.
template <int RELU>
__global__ __launch_bounds__(256) void k_agg(const float* __restrict__ hW,
                                             const int* __restrict__ rp,
                                             const int* __restrict__ cnt,
                                             const int2* __restrict__ pack,
                                             const float* __restrict__ dinv,
                                             const float* __restrict__ bias,
                                             float* __restrict__ hout, int N) {
    int lane = threadIdx.x & 63;
    int n = blockIdx.x * 4 + (threadIdx.x >> 6);
    if (n >= N) return;
    int grp = lane >> 4;                  // 0..3
    int ch4 = (lane & 15) << 2;           // channel offset (float)
    int r0 = rp[n];
    int cg = (cnt[n] + 7) & ~7;
    float4 accA = {0.f, 0.f, 0.f, 0.f};
    float4 accB = {0.f, 0.f, 0.f, 0.f};
    for (int i = 0; i < cg; i += 8) {
        int2 pA = pack[r0 + i + grp];
        int2 pB = pack[r0 + i + 4 + grp];
        float vA = __int_as_float(pA.y);
        float vB = __int_as_float(pB.y);
        const float4 ra = *(const float4*)&hW[pA.x * D + ch4];
        const float4 rb = *(const float4*)&hW[pB.x * D + ch4];
        accA.x += vA * ra.x; accA.y += vA * ra.y; accA.z += vA * ra.z; accA.w += vA * ra.w;
        accB.x += vB * rb.x; accB.y += vB * rb.y; accB.z += vB * rb.z; accB.w += vB * rb.w;
    }
    float4 p;
    p.x = accA.x + accB.x; p.y = accA.y + accB.y;
    p.z = accA.z + accB.z; p.w = accA.w + accB.w;
    p.x += __shfl_xor(p.x, 16); p.y += __shfl_xor(p.y, 16);
    p.z += __shfl_xor(p.z, 16); p.w += __shfl_xor(p.w, 16);
    p.x += __shfl_xor(p.x, 32); p.y += __shfl_xor(p.y, 32);
    p.z += __shfl_xor(p.z, 32); p.w += __shfl_xor(p.w, 32);
    if (grp == 0) {                       // lanes 0..15 hold+store the row
        float dv = dinv[n];
        float s2 = dv * dv;
        float4 sf = *(const float4*)&hW[n * D + ch4];
        float4 bv = *(const float4*)&bias[ch4];
        float4 o;
        o.x = p.x + s2 * sf.x + bv.x;
        o.y = p.y + s2 * sf.y + bv.y;
        o.z = p.z + s2 * sf.z + bv.z;
        o.w = p.w + s2 * sf.w + bv.w;
        if (RELU) {
            o.x = fmaxf(o.x, 0.f); o.y = fmaxf(o.y, 0.f);
            o.z = fmaxf(o.z, 0.f); o.w = fmaxf(o.w, 0.f);
        }
        *(float4*)&hout[n * D + ch4] = o;
    }
}

// ---------------- final layer: aggregate + MLP readout + graph-sum ----------------
__global__ __launch_bounds__(256) void k_agg_readout(const float* __restrict__ hW,
                                                     const int* __restrict__ rp,
                                                     const int* __restrict__ cnt,
                                                     const int2* __restrict__ pack,
                                                     const float* __restrict__ dinv,
                                                     const float* __restrict__ bias,
                                                     const float* __restrict__ RW1,
                                                     const float* __restrict__ Rb1,
                                                     const float* __restrict__ RW2,
                                                     const float* __restrict__ Rb2,
                                                     const int* __restrict__ batch,
                                                     float* __restrict__ gsum, int N) {
    __shared__ float sh[4][64];
    int lane = threadIdx.x & 63;
    int widx = threadIdx.x >> 6;
    int n = blockIdx.x * 4 + widx;
    if (n >= N) return;                   // all LDS traffic is wave-internal
    int grp = lane >> 4;
    int ch4 = (lane & 15) << 2;
    int r0 = rp[n];
    int cg = (cnt[n] + 7) & ~7;
    float4 accA = {0.f, 0.f, 0.f, 0.f};
    float4 accB = {0.f, 0.f, 0.f, 0.f};
    for (int i = 0; i < cg; i += 8) {
        int2 pA = pack[r0 + i + grp];
        int2 pB = pack[r0 + i + 4 + grp];
        float vA = __int_as_float(pA.y);
        float vB = __int_as_float(pB.y);
        const float4 ra = *(const float4*)&hW[pA.x * D + ch4];
        const float4 rb = *(const float4*)&hW[pB.x * D + ch4];
        accA.x += vA * ra.x; accA.y += vA * ra.y; accA.z += vA * ra.z; accA.w += vA * ra.w;
        accB.x += vB * rb.x; accB.y += vB * rb.y; accB.z += vB * rb.z; accB.w += vB * rb.w;
    }
    float4 p;
    p.x = accA.x + accB.x; p.y = accA.y + accB.y;
    p.z = accA.z + accB.z; p.w = accA.w + accB.w;
    p.x += __shfl_xor(p.x, 16); p.y += __shfl_xor(p.y, 16);
    p.z += __shfl_xor(p.z, 16); p.w += __shfl_xor(p.w, 16);
    p.x += __shfl_xor(p.x, 32); p.y += __shfl_xor(p.y, 32);
    p.z += __shfl_xor(p.z, 32); p.w += __shfl_xor(p.w, 32);
    if (grp == 0) {
        float dv = dinv[n];
        float s2 = dv * dv;
        float4 sf = *(const float4*)&hW[n * D + ch4];
        float4 bv = *(const float4*)&bias[ch4];
        float4 o;                          // h2: no relu on last GCN layer
        o.x = p.x + s2 * sf.x + bv.x;
        o.y = p.y + s2 * sf.y + bv.y;
        o.z = p.z + s2 * sf.z + bv.z;
        o.w = p.w + s2 * sf.w + bv.w;
        *(float4*)&sh[widx][ch4] = o;
    }
    // MLP: all 64 lanes. unit = lane&31, half = lane>>5 covers 32 cc each.
    int unit = lane & 31, half = lane >> 5;
    float m = 0.0f;
    #pragma unroll
    for (int j = 0; j < 32; j++) {
        int cc = half * 32 + j;
        m += sh[widx][cc] * RW1[cc * 32 + unit];
    }
    m += __shfl_xor(m, 32);               // combine the two cc-halves
    m += Rb1[unit];
    m = fmaxf(m, 0.0f);
    float y = m * RW2[unit];
    #pragma unroll
    for (int off = 16; off >= 1; off >>= 1) y += __shfl_xor(y, off);
    if (lane == 0) atomicAdd(&gsum[batch[n]], y + Rb2[0]);
}

// ---------------- scatter-mean finalize ----------------
__global__ __launch_bounds__(256) void k_final(const float* __restrict__ gsum,
                                               const int* __restrict__ gcnt,
                                               float* __restrict__ out, int G) {
    int g = blockIdx.x * 256 + threadIdx.x;
    if (g < G) out[g] = gsum[g] / fmaxf((float)gcnt[g], 1.0f);
}

extern "C" void kernel_launch(void* const* d_in, const int* in_sizes, int n_in,
                              void* d_out, int out_size, void* d_ws, size_t ws_size,
                              hipStream_t stream) {
    const float* x     = (const float*)d_in[0];
    const int*   ei    = (const int*)d_in[1];
    const float* ea    = (const float*)d_in[2];
    const int*   batch = (const int*)d_in[3];
    const float* W0 = (const float*)d_in[4];
    const float* b0 = (const float*)d_in[5];
    const float* W1 = (const float*)d_in[6];
    const float* b1 = (const float*)d_in[7];
    const float* W2 = (const float*)d_in[8];
    const float* b2 = (const float*)d_in[9];
    const float* RW1 = (const float*)d_in[10];
    const float* Rb1 = (const float*)d_in[11];
    const float* RW2 = (const float*)d_in[12];
    const float* Rb2 = (const float*)d_in[13];

    const int N = in_sizes[0] / D;        // 100000
    const int E = in_sizes[1] / 2;        // 1200000
    const int G = out_size;               // 512
    const int* src = ei;
    const int* dst = ei + E;

    const size_t EP = (size_t)E + 8 * (size_t)N;   // padded CSR capacity (x8 groups)

    // ---- workspace layout ----
    char* p = (char*)d_ws;
    // zero-init region (one memset): deg, cnt, fill, gsum, gcnt, pack
    float* deg   = (float*)p;             p += (size_t)N * 4;
    int*   cnt   = (int*)p;               p += (size_t)N * 4;
    int*   fill  = (int*)p;               p += (size_t)N * 4;
    float* gsum  = (float*)p;             p += (size_t)NG * 4;
    int*   gcnt  = (int*)p;               p += (size_t)NG * 4;
    int2*  pack  = (int2*)p;              p += EP * 8;
    size_t zbytes = (size_t)(3 * N + 2 * NG) * 4 + EP * 8;
    // no-init region
    float* dinv  = (float*)p;             p += (size_t)N * 4;
    int*   rp    = (int*)p;               p += (size_t)N * 4;
    int*   bsums = (int*)p;               p += (size_t)512 * 4;
    float* hW    = (float*)p;             p += (size_t)N * D * 4;
    float* h     = (float*)p;             p += (size_t)N * D * 4;

    hipMemsetAsync(d_ws, 0, zbytes, stream);

    int ebl = (E + 255) / 256;
    int nbl = (N + 255) / 256;            // 391
    k_edge_deg<<<ebl, 256, 0, stream>>>(src, dst, ea, deg, cnt, E);
    k_node_dinv<<<nbl, 256, 0, stream>>>(deg, dinv, batch, gcnt, N);
    k_scan1<<<nbl, 256, 0, stream>>>(cnt, rp, bsums, N);
    k_scan2<<<1, 512, 0, stream>>>(bsums, nbl);
    k_scan3<<<nbl, 256, 0, stream>>>(rp, bsums, N);
    k_fill<<<ebl, 256, 0, stream>>>(src, dst, ea, dinv, rp, fill, pack, E);

    int gemm_bl = (N + 63) / 64;          // 1563
    int agg_bl  = (N + 3) / 4;            // 25000

    // layer 0: x -> h
    k_gemm<<<gemm_bl, 256, 0, stream>>>(x, W0, hW, N);
    k_agg<1><<<agg_bl, 256, 0, stream>>>(hW, rp, cnt, pack, dinv, b0, h, N);
    // layer 1: h -> h
    k_gemm<<<gemm_bl, 256, 0, stream>>>(h, W1, hW, N);
    k_agg<1><<<agg_bl, 256, 0, stream>>>(hW, rp, cnt, pack, dinv, b1, h, N);
    // layer 2 + readout + graph scatter
    k_gemm<<<gemm_bl, 256, 0, stream>>>(h, W2, hW, N);
    k_agg_readout<<<agg_bl, 256, 0, stream>>>(hW, rp, cnt, pack, dinv, b2,
                                              RW1, Rb1, RW2, Rb2, batch, gsum, N);

    k_final<<<(G + 255) / 256, 256, 0, stream>>>(gsum, gcnt, (float*)d_out, G);
}